// Round 12
// baseline (102.079 us; speedup 1.0000x reference)
//
#include <hip/hip_runtime.h>
#include <math.h>

#define N_ROWS 4096
#define DIM 256
constexpr float INV_T = 10.0f;

#define NT 32                   // 4096 / 128 tiles per view side
#define NTILES 528              // NT*(NT+1)/2 upper-triangular tiles
#define TOTAL_TILES (2 * NTILES)  // 1056
#define GRID_BLOCKS 512         // 2 blocks/CU (64 KB LDS) x 256 CUs -> all co-resident
#define BM 128
#define PSTRIDE 512             // [2x128 row partials | 2x128 col partials]
#define MAGIC1 0x1F2E3D4Cu
#define MAGIC2 0x5B6A7988u      // distinct magics; ws poison 0xAAAAAAAA matches neither

typedef __attribute__((ext_vector_type(4))) float floatx4;
typedef __attribute__((address_space(3))) unsigned int lds_uint;
typedef const __attribute__((address_space(1))) unsigned int glb_uint;

#define ST_DEV(p, v) __hip_atomic_store((p), (v), __ATOMIC_RELAXED, __HIP_MEMORY_SCOPE_AGENT)
#define LD_DEV(p)    __hip_atomic_load((p), __ATOMIC_RELAXED, __HIP_MEMORY_SCOPE_AGENT)

// Single fused kernel: normalize -> [grid barrier] -> symmetric fp8 GEMM with
// exp-rowsum epilogue -> [grid barrier] -> per-row gather + loss.
// Grid barriers are flag-array spins (equality vs magic, so 0xAA poison is
// inert and phase-1/phase-2 flags can't be confused). All cross-phase writes
// use device-scope (sc1) stores -- per-store write-through, NOT the per-block
// buffer_wbl2 L2 scan that made round 2 catastrophic. vmcnt(0) drain before
// each flag set orders data before the flag.
__global__ __launch_bounds__(256) void ntxent_fused(
    const float* __restrict__ z_i, const float* __restrict__ z_j,
    unsigned char* __restrict__ R0, unsigned char* __restrict__ R1,
    float* __restrict__ pos, float* __restrict__ part,
    unsigned int* __restrict__ flag1, unsigned int* __restrict__ flag2,
    float* __restrict__ out)
{
    __shared__ unsigned char As[BM * DIM];   // 32 KB
    __shared__ unsigned char Bs[BM * DIM];   // 32 KB -> 64 KB => 2 blocks/CU

    int tid = threadIdx.x;
    int lane = tid & 63;
    int wave = tid >> 6;
    int bid = blockIdx.x;

    // ---------------- Phase 1: normalize 8 row-pairs per block ----------------
    if (bid == 0 && tid == 0) ST_DEV(out, 0.0f);

    #pragma unroll
    for (int i = 0; i < 2; ++i) {
        int row = bid * 8 + wave * 2 + i;                // 0..4095
        float4 a = ((const float4*)(z_i + (size_t)row * DIM))[lane];
        float4 b = ((const float4*)(z_j + (size_t)row * DIM))[lane];
        float ssa = a.x*a.x + a.y*a.y + a.z*a.z + a.w*a.w;
        float ssb = b.x*b.x + b.y*b.y + b.z*b.z + b.w*b.w;
        float dab = a.x*b.x + a.y*b.y + a.z*b.z + a.w*b.w;
        #pragma unroll
        for (int off = 1; off < 64; off <<= 1) {
            ssa += __shfl_xor(ssa, off);
            ssb += __shfl_xor(ssb, off);
            dab += __shfl_xor(dab, off);
        }
        float ra = rsqrtf(ssa);
        float rb = rsqrtf(ssb);
        int va = __builtin_amdgcn_cvt_pk_fp8_f32(a.x * ra, a.y * ra, 0, false);
        va     = __builtin_amdgcn_cvt_pk_fp8_f32(a.z * ra, a.w * ra, va, true);
        int vb = __builtin_amdgcn_cvt_pk_fp8_f32(b.x * rb, b.y * rb, 0, false);
        vb     = __builtin_amdgcn_cvt_pk_fp8_f32(b.z * rb, b.w * rb, vb, true);
        ST_DEV((int*)(R1 + (size_t)row * DIM + lane * 4), va);   // zi_norm
        ST_DEV((int*)(R0 + (size_t)row * DIM + lane * 4), vb);   // zj_norm
        if (lane == 0) ST_DEV(&pos[row], dab * ra * rb * INV_T);
    }

    // ---------------- grid barrier helper ----------------
    auto gridbar = [&](unsigned int* flags, unsigned int magic) {
        asm volatile("s_waitcnt vmcnt(0)" ::: "memory");  // drain my sc1 stores
        __syncthreads();                                  // whole block arrived
        if (tid < 64) {
            if (tid == 0) ST_DEV(&flags[bid], magic);
            for (;;) {
                unsigned int ok = 1u;
                #pragma unroll
                for (int i = 0; i < 8; ++i)
                    ok &= (LD_DEV(&flags[tid * 8 + i]) == magic) ? 1u : 0u;
                if (__ballot(ok != 0u) == ~0ull) break;
                __builtin_amdgcn_s_sleep(4);
            }
        }
        __syncthreads();
    };

    gridbar(flag1, MAGIC1);

    // ---------------- Phase 2: fp8 GEMM tiles (round-11 structure) ----------------
    int wy = wave >> 1, wx = wave & 1;
    int m = lane & 15, q = lane >> 4;

    for (int tt = bid; tt < TOTAL_TILES; tt += GRID_BLOCKS) {
        int view = (tt >= NTILES) ? 1 : 0;
        int tile = tt - view * NTILES;
        const unsigned char* R = view ? R1 : R0;
        float* P = part + (size_t)tt * PSTRIDE;

        int t = tile, by = 0;
        while (t >= NT - by) { t -= NT - by; ++by; }
        int bx = by + t;
        int rT = by * BM, cT = bx * BM;

        __syncthreads();   // previous tile's LDS readers done before overwrite
        #pragma unroll
        for (int stp = 0; stp < 8; ++stp) {
            int s = stp * 256 + tid;              // 16B slot (128 rows x 16 chunk16)
            int row = s >> 4, p = s & 15;
            int cg = p ^ (row & 15);              // source-side swizzle
            const unsigned char* ga = R + (size_t)(rT + row) * DIM + cg * 16;
            const unsigned char* gb = R + (size_t)(cT + row) * DIM + cg * 16;
            __builtin_amdgcn_global_load_lds((glb_uint*)ga, (lds_uint*)&As[s * 16], 16, 0, 0);
            __builtin_amdgcn_global_load_lds((glb_uint*)gb, (lds_uint*)&Bs[s * 16], 16, 0, 0);
        }
        __syncthreads();   // compiler adds vmcnt(0): DMA landed

        floatx4 acc[4][4] = {};
        #pragma unroll
        for (int kk = 0; kk < 8; ++kk) {
            long af[4], bf[4];
            int c = kk * 4 + q;
            int ch = c >> 1, hh = (c & 1) * 8;
            #pragma unroll
            for (int tr = 0; tr < 4; ++tr) {
                int ra = wy * 64 + tr * 16 + m;
                af[tr] = *(const long*)&As[ra * DIM + (ch ^ (ra & 15)) * 16 + hh];
                int rb = wx * 64 + tr * 16 + m;
                bf[tr] = *(const long*)&Bs[rb * DIM + (ch ^ (rb & 15)) * 16 + hh];
            }
            #pragma unroll
            for (int i = 0; i < 4; ++i)
                #pragma unroll
                for (int j = 0; j < 4; ++j)
                    acc[i][j] = __builtin_amdgcn_mfma_f32_16x16x32_fp8_fp8(af[i], bf[j], acc[i][j], 0, 0, 0);
        }

        // Epilogue. C/D layout: col = m, row = q*4 + r.
        float rs[4][4] = {};
        float cs[4] = {0.f, 0.f, 0.f, 0.f};
        #pragma unroll
        for (int i = 0; i < 4; ++i)
            #pragma unroll
            for (int j = 0; j < 4; ++j) {
                int gcol = cT + wx * 64 + j * 16 + m;
                #pragma unroll
                for (int r = 0; r < 4; ++r) {
                    int grow = rT + wy * 64 + i * 16 + q * 4 + r;
                    float e = (grow == gcol) ? 0.0f : __expf(acc[i][j][r] * INV_T);
                    rs[i][r] += e;
                    cs[j] += e;
                }
            }
        #pragma unroll
        for (int off = 1; off < 16; off <<= 1)
            #pragma unroll
            for (int i = 0; i < 4; ++i)
                #pragma unroll
                for (int r = 0; r < 4; ++r)
                    rs[i][r] += __shfl_xor(rs[i][r], off);
        if (m == 0) {
            #pragma unroll
            for (int i = 0; i < 4; ++i)
                #pragma unroll
                for (int r = 0; r < 4; ++r)
                    ST_DEV(&P[wx * 128 + wy * 64 + i * 16 + q * 4 + r], rs[i][r]);
        }
        #pragma unroll
        for (int off = 16; off < 64; off <<= 1)
            #pragma unroll
            for (int j = 0; j < 4; ++j)
                cs[j] += __shfl_xor(cs[j], off);
        if (q == 0) {
            #pragma unroll
            for (int j = 0; j < 4; ++j)
                ST_DEV(&P[256 + wy * 128 + wx * 64 + j * 16 + m], (bx == by) ? 0.0f : cs[j]);
        }
    }

    gridbar(flag2, MAGIC2);

    // ---------------- Phase 3: gather + loss (16 rows per block) ----------------
    int rown = lane & 3;
    int slice = lane >> 2;                        // 16 gather slices per row
    int g = bid * 16 + wave * 4 + rown;           // 0..8191
    int v = g >> 12, r = g & (N_ROWS - 1);
    int b7 = r >> 7, l = r & 127;
    const float* Pv = part + (size_t)v * NTILES * PSTRIDE;

    float d = 0.f;
    int t0 = b7 * NT - (b7 * (b7 - 1)) / 2;
    for (int k = slice; k < NT - b7; k += 16) {
        const float* T = Pv + (size_t)(t0 + k) * PSTRIDE;
        d += T[l] + T[128 + l];
    }
    for (int by2 = slice; by2 <= b7; by2 += 16) {
        int tb = by2 * NT - (by2 * (by2 - 1)) / 2 + (b7 - by2);
        const float* T = Pv + (size_t)tb * PSTRIDE;
        d += T[256 + l] + T[384 + l];
    }
    #pragma unroll
    for (int off = 4; off < 64; off <<= 1) d += __shfl_xor(d, off);
    float p = pos[r];
    float s = __logf(d + __expf(p)) - p;
    s += __shfl_xor(s, 1);
    s += __shfl_xor(s, 2);                        // sum of this wave's 4 rows
    float* red = (float*)As;                      // LDS free after barrier 2
    if (lane == 0) red[wave] = s;
    __syncthreads();
    if (tid == 0)
        __hip_atomic_fetch_add(out, (red[0] + red[1] + red[2] + red[3]) * (1.0f / (2 * N_ROWS)),
                               __ATOMIC_RELAXED, __HIP_MEMORY_SCOPE_AGENT);
}

extern "C" void kernel_launch(void* const* d_in, const int* in_sizes, int n_in,
                              void* d_out, int out_size, void* d_ws, size_t ws_size,
                              hipStream_t stream) {
    const float* z_i = (const float*)d_in[0];
    const float* z_j = (const float*)d_in[1];
    char* ws = (char*)d_ws;
    unsigned char* R0 = (unsigned char*)ws;                          // 1 MB fp8
    unsigned char* R1 = (unsigned char*)(ws + (1u << 20));           // 1 MB fp8
    float* pos  = (float*)(ws + (2u << 20));                         // 16 KB
    float* part = (float*)(ws + (2u << 20) + (64u << 10));           // 2.16 MB
    unsigned int* flag1 = (unsigned int*)(ws + (5u << 20));          // 2 KB
    unsigned int* flag2 = (unsigned int*)(ws + (5u << 20) + 4096);   // 2 KB

    ntxent_fused<<<GRID_BLOCKS, 256, 0, stream>>>(z_i, z_j, R0, R1, pos, part,
                                                  flag1, flag2, (float*)d_out);
}

// Round 13
// 95.433 us; speedup vs baseline: 1.0696x; 1.0696x over previous
//
#include <hip/hip_runtime.h>
#include <math.h>

#define N_ROWS 4096
#define DIM 256
constexpr float INV_T = 10.0f;

#define NT 32                    // 4096 / 128 tiles per view side
#define NTILES 528               // NT*(NT+1)/2 upper-triangular tiles
#define TOTAL_TILES (2 * NTILES) // 1056
#define FINALIZERS 32            // last 32 ticket-holders run the gather
#define BM 128
#define PSTRIDE 512              // [2x128 row partials (per wx) | 2x128 col partials (per wy)]

typedef __attribute__((ext_vector_type(4))) float floatx4;
typedef __attribute__((address_space(3))) unsigned int lds_uint;
typedef const __attribute__((address_space(1))) unsigned int glb_uint;

#define ST_DEV(p, v) __hip_atomic_store((p), (v), __ATOMIC_RELAXED, __HIP_MEMORY_SCOPE_AGENT)
#define LD_DEV(p)    __hip_atomic_load((p), __ATOMIC_RELAXED, __HIP_MEMORY_SCOPE_AGENT)

// Kernel 1: one wave per row. L2-normalize; fp8 e4m3 row-major to R0 (zj_n) /
// R1 (zi_n); pos[r] = dot(zi_n,zj_n)*10 fp32. Zeroes out + completion counter.
__global__ __launch_bounds__(256) void normalize_kernel(
    const float* __restrict__ z_i, const float* __restrict__ z_j,
    unsigned char* __restrict__ R0, unsigned char* __restrict__ R1,
    float* __restrict__ pos, int* __restrict__ counter, float* __restrict__ out)
{
    if (blockIdx.x == 0 && threadIdx.x == 0) { out[0] = 0.0f; *counter = 0; }

    int wave = threadIdx.x >> 6;
    int lane = threadIdx.x & 63;
    int row = blockIdx.x * 4 + wave;

    float4 a = ((const float4*)(z_i + (size_t)row * DIM))[lane];   // k = lane*4..+3
    float4 b = ((const float4*)(z_j + (size_t)row * DIM))[lane];

    float ssa = a.x*a.x + a.y*a.y + a.z*a.z + a.w*a.w;
    float ssb = b.x*b.x + b.y*b.y + b.z*b.z + b.w*b.w;
    float dab = a.x*b.x + a.y*b.y + a.z*b.z + a.w*b.w;
    #pragma unroll
    for (int off = 1; off < 64; off <<= 1) {
        ssa += __shfl_xor(ssa, off);
        ssb += __shfl_xor(ssb, off);
        dab += __shfl_xor(dab, off);
    }
    float ra = rsqrtf(ssa);
    float rb = rsqrtf(ssb);

    int va = __builtin_amdgcn_cvt_pk_fp8_f32(a.x * ra, a.y * ra, 0, false);
    va     = __builtin_amdgcn_cvt_pk_fp8_f32(a.z * ra, a.w * ra, va, true);
    int vb = __builtin_amdgcn_cvt_pk_fp8_f32(b.x * rb, b.y * rb, 0, false);
    vb     = __builtin_amdgcn_cvt_pk_fp8_f32(b.z * rb, b.w * rb, vb, true);

    *(int*)(R1 + (size_t)row * DIM + lane * 4) = va;   // zi_norm
    *(int*)(R0 + (size_t)row * DIM + lane * 4) = vb;   // zj_norm

    if (lane == 0) pos[row] = dab * ra * rb * INV_T;
}

// Kernel 2: symmetric fused fp8 GEMM (R11 structure) + counter-fused finalize.
// ONE-SHOT full-K staging via global_load_lds(16B) with source-side 16B swizzle
// (slot16 p of row r holds chunk16 p^(r&15)); single barrier; 8 K-steps of
// ds_read_b64 + mfma_f32_16x16x32_fp8_fp8. Epilogue exp(10*S), diag excluded;
// partials written with DEVICE-SCOPE stores (cross-XCD visible at the
// coherence point -- R12-validated). Then vmcnt(0) drain + ticket; the last 32
// tickets spin until all 1056 arrived (<=31 stragglers vs 512 resident slots:
// no deadlock) and each gathers 256 rows -> loss atomicAdd. NO threadfence.
__global__ __launch_bounds__(256) void gemm_sym(
    const unsigned char* __restrict__ R0,
    const unsigned char* __restrict__ R1,
    float* __restrict__ part,             // [2][NTILES][PSTRIDE]
    const float* __restrict__ pos,
    int* __restrict__ counter,
    float* __restrict__ out)
{
    __shared__ unsigned char As[BM * DIM];   // 32 KB
    __shared__ unsigned char Bs[BM * DIM];   // 32 KB -> 64 KB, 2 blocks/CU

    int view = blockIdx.y;
    const unsigned char* R = view ? R1 : R0;
    float* P = part + (size_t)(view * NTILES + blockIdx.x) * PSTRIDE;

    // triangular decode: blockIdx.x -> (by, bx), bx >= by
    int t = blockIdx.x;
    int by = 0;
    while (t >= NT - by) { t -= NT - by; ++by; }
    int bx = by + t;
    int rT = by * BM, cT = bx * BM;

    int tid = threadIdx.x;
    int lane = tid & 63;
    int wave = tid >> 6;
    int wy = wave >> 1, wx = wave & 1;
    int m = lane & 15, q = lane >> 4;

    // Stage both tiles: 2048 16B-slots each (128 rows x 16 chunk16).
    #pragma unroll
    for (int stp = 0; stp < 8; ++stp) {
        int s = stp * 256 + tid;
        int row = s >> 4, p = s & 15;
        int cg = p ^ (row & 15);
        const unsigned char* ga = R + (size_t)(rT + row) * DIM + cg * 16;
        const unsigned char* gb = R + (size_t)(cT + row) * DIM + cg * 16;
        __builtin_amdgcn_global_load_lds((glb_uint*)ga, (lds_uint*)&As[s * 16], 16, 0, 0);
        __builtin_amdgcn_global_load_lds((glb_uint*)gb, (lds_uint*)&Bs[s * 16], 16, 0, 0);
    }
    __syncthreads();   // single barrier (compiler adds the vmcnt(0) drain)

    floatx4 acc[4][4] = {};
    #pragma unroll
    for (int kk = 0; kk < 8; ++kk) {
        long af[4], bf[4];
        int c = kk * 4 + q;
        int ch = c >> 1, hh = (c & 1) * 8;
        #pragma unroll
        for (int tr = 0; tr < 4; ++tr) {
            int ra = wy * 64 + tr * 16 + m;
            af[tr] = *(const long*)&As[ra * DIM + (ch ^ (ra & 15)) * 16 + hh];
            int rb = wx * 64 + tr * 16 + m;
            bf[tr] = *(const long*)&Bs[rb * DIM + (ch ^ (rb & 15)) * 16 + hh];
        }
        #pragma unroll
        for (int i = 0; i < 4; ++i)
            #pragma unroll
            for (int j = 0; j < 4; ++j)
                acc[i][j] = __builtin_amdgcn_mfma_f32_16x16x32_fp8_fp8(af[i], bf[j], acc[i][j], 0, 0, 0);
    }

    // Epilogue. C/D layout: col = m, row = q*4 + r (dtype-independent).
    float rs[4][4] = {};
    float cs[4] = {0.f, 0.f, 0.f, 0.f};
    #pragma unroll
    for (int i = 0; i < 4; ++i)
        #pragma unroll
        for (int j = 0; j < 4; ++j) {
            int gcol = cT + wx * 64 + j * 16 + m;
            #pragma unroll
            for (int r = 0; r < 4; ++r) {
                int grow = rT + wy * 64 + i * 16 + q * 4 + r;
                float e = (grow == gcol) ? 0.0f : __expf(acc[i][j][r] * INV_T);
                rs[i][r] += e;
                cs[j] += e;
            }
        }
    #pragma unroll
    for (int off = 1; off < 16; off <<= 1)
        #pragma unroll
        for (int i = 0; i < 4; ++i)
            #pragma unroll
            for (int r = 0; r < 4; ++r)
                rs[i][r] += __shfl_xor(rs[i][r], off);
    if (m == 0) {
        #pragma unroll
        for (int i = 0; i < 4; ++i)
            #pragma unroll
            for (int r = 0; r < 4; ++r)
                ST_DEV(&P[wx * 128 + wy * 64 + i * 16 + q * 4 + r], rs[i][r]);
    }
    #pragma unroll
    for (int off = 16; off < 64; off <<= 1)
        #pragma unroll
        for (int j = 0; j < 4; ++j)
            cs[j] += __shfl_xor(cs[j], off);
    if (q == 0) {
        #pragma unroll
        for (int j = 0; j < 4; ++j)
            ST_DEV(&P[256 + wy * 128 + wx * 64 + j * 16 + m], (bx == by) ? 0.0f : cs[j]);
    }

    // ---- completion ticket (device-scope stores drained first) ----
    asm volatile("s_waitcnt vmcnt(0)" ::: "memory");
    __syncthreads();
    int* ticket_s = (int*)As;                 // LDS dead past this point
    float* red = (float*)As + 2;
    if (tid == 0)
        *ticket_s = __hip_atomic_fetch_add(counter, 1, __ATOMIC_RELAXED, __HIP_MEMORY_SCOPE_AGENT);
    __syncthreads();
    int ticket = *ticket_s;
    if (ticket < TOTAL_TILES - FINALIZERS) return;

    // ---- finalize slice: wait for all tiles, gather 256 rows, reduce ----
    if (tid == 0) {
        while (LD_DEV(counter) < TOTAL_TILES) __builtin_amdgcn_s_sleep(2);
    }
    __syncthreads();

    int slice = ticket - (TOTAL_TILES - FINALIZERS);
    int g = slice * 256 + tid;                // 0..8191
    int v = g >> 12, r = g & (N_ROWS - 1);
    int b = r >> 7, l = r & 127;
    const float* Pv = part + (size_t)v * NTILES * PSTRIDE;

    float d = 0.f;
    int t0 = b * NT - (b * (b - 1)) / 2;      // tile (b, b)
    for (int k = 0; k < NT - b; ++k) {        // row parts: tiles (b, bx>=b)
        const float* T = Pv + (size_t)(t0 + k) * PSTRIDE;
        d += T[l] + T[128 + l];
    }
    for (int by2 = 0; by2 <= b; ++by2) {      // col parts: tiles (by<=b, b)
        int tb = by2 * NT - (by2 * (by2 - 1)) / 2 + (b - by2);
        const float* T = Pv + (size_t)tb * PSTRIDE;
        d += T[256 + l] + T[384 + l];
    }
    float p = pos[r];
    float s = __logf(d + __expf(p)) - p;
    #pragma unroll
    for (int off = 1; off < 64; off <<= 1) s += __shfl_xor(s, off);
    if (lane == 0) red[wave] = s;
    __syncthreads();
    if (tid == 0)
        __hip_atomic_fetch_add(out, (red[0] + red[1] + red[2] + red[3]) * (1.0f / (2 * N_ROWS)),
                               __ATOMIC_RELAXED, __HIP_MEMORY_SCOPE_AGENT);
}

extern "C" void kernel_launch(void* const* d_in, const int* in_sizes, int n_in,
                              void* d_out, int out_size, void* d_ws, size_t ws_size,
                              hipStream_t stream) {
    const float* z_i = (const float*)d_in[0];
    const float* z_j = (const float*)d_in[1];
    char* ws = (char*)d_ws;
    unsigned char* R0 = (unsigned char*)ws;                          // 1 MB fp8
    unsigned char* R1 = (unsigned char*)(ws + (1u << 20));           // 1 MB fp8
    float* pos  = (float*)(ws + (2u << 20));                         // 16 KB
    float* part = (float*)(ws + (2u << 20) + (64u << 10));           // 2.16 MB
    int* counter = (int*)(ws + (5u << 20));                          // 4 B

    normalize_kernel<<<N_ROWS / 4, 256, 0, stream>>>(z_i, z_j, R0, R1, pos,
                                                     counter, (float*)d_out);
    dim3 grid(NTILES, 2);
    gemm_sym<<<grid, 256, 0, stream>>>(R0, R1, part, pos, counter, (float*)d_out);
}

// Round 14
// 88.700 us; speedup vs baseline: 1.1508x; 1.0759x over previous
//
#include <hip/hip_runtime.h>
#include <math.h>

#define N_ROWS 4096
#define DIM 256
constexpr float INV_T = 10.0f;

#define NT 32                    // 4096 / 128 tiles per view side
#define NTILES 528               // NT*(NT+1)/2 upper-triangular tiles
#define TOTAL_TILES (2 * NTILES) // 1056
#define GRID_BLOCKS 512          // 2 blocks/CU (64 KB LDS) -> all co-resident, ~2 tiles each
#define BM 128
#define PSTRIDE 512              // [2x128 row partials (per wx) | 2x128 col partials (per wy)]

typedef __attribute__((ext_vector_type(4))) float floatx4;
typedef __attribute__((address_space(3))) unsigned int lds_uint;
typedef const __attribute__((address_space(1))) unsigned int glb_uint;

// Kernel 1: one wave per row. L2-normalize; fp8 e4m3 row-major to R0 (zj_n) /
// R1 (zi_n); pos[r] = dot(zi_n,zj_n)*10 fp32. Thread (0,0) zeroes out.
__global__ __launch_bounds__(256) void normalize_kernel(
    const float* __restrict__ z_i, const float* __restrict__ z_j,
    unsigned char* __restrict__ R0, unsigned char* __restrict__ R1,
    float* __restrict__ pos, float* __restrict__ out)
{
    if (blockIdx.x == 0 && threadIdx.x == 0) out[0] = 0.0f;

    int wave = threadIdx.x >> 6;
    int lane = threadIdx.x & 63;
    int row = blockIdx.x * 4 + wave;

    float4 a = ((const float4*)(z_i + (size_t)row * DIM))[lane];   // k = lane*4..+3
    float4 b = ((const float4*)(z_j + (size_t)row * DIM))[lane];

    float ssa = a.x*a.x + a.y*a.y + a.z*a.z + a.w*a.w;
    float ssb = b.x*b.x + b.y*b.y + b.z*b.z + b.w*b.w;
    float dab = a.x*b.x + a.y*b.y + a.z*b.z + a.w*b.w;
    #pragma unroll
    for (int off = 1; off < 64; off <<= 1) {
        ssa += __shfl_xor(ssa, off);
        ssb += __shfl_xor(ssb, off);
        dab += __shfl_xor(dab, off);
    }
    float ra = rsqrtf(ssa);
    float rb = rsqrtf(ssb);

    int va = __builtin_amdgcn_cvt_pk_fp8_f32(a.x * ra, a.y * ra, 0, false);
    va     = __builtin_amdgcn_cvt_pk_fp8_f32(a.z * ra, a.w * ra, va, true);
    int vb = __builtin_amdgcn_cvt_pk_fp8_f32(b.x * rb, b.y * rb, 0, false);
    vb     = __builtin_amdgcn_cvt_pk_fp8_f32(b.z * rb, b.w * rb, vb, true);

    *(int*)(R1 + (size_t)row * DIM + lane * 4) = va;   // zi_norm
    *(int*)(R0 + (size_t)row * DIM + lane * 4) = vb;   // zj_norm

    if (lane == 0) pos[row] = dab * ra * rb * INV_T;
}

// Kernel 2: PERSISTENT symmetric fused fp8 GEMM, 512 blocks x ~2 tiles.
// Per tile: one-shot full-K staging via global_load_lds(16B) with source-side
// 16B swizzle (slot16 p of row r holds chunk16 p^(r&15)); single drain
// barrier; 8 K-steps of ds_read_b64 + mfma_f32_16x16x32_fp8_fp8.
// KEY: the NEXT tile's DMAs are issued right after the k-loop's read-fence
// barrier, so they fly during the current tile's register-only epilogue.
// Epilogue: exp(10*S), diag excluded; ROW partials per (tile,wx-wave), COL
// partials per (tile,wy-wave), plain coalesced stores, unique slot per wave.
// No atomics, no counter, no fence (session rules R2/R6/R13).
__global__ __launch_bounds__(256) void gemm_sym(
    const unsigned char* __restrict__ R0,
    const unsigned char* __restrict__ R1,
    float* __restrict__ part)             // [2][NTILES][PSTRIDE]
{
    __shared__ unsigned char As[BM * DIM];   // 32 KB
    __shared__ unsigned char Bs[BM * DIM];   // 32 KB -> 64 KB, 2 blocks/CU

    int tid = threadIdx.x;
    int lane = tid & 63;
    int wave = tid >> 6;
    int wy = wave >> 1, wx = wave & 1;
    int m = lane & 15, q = lane >> 4;

    // decode tile id -> (view, by, bx)
    auto decode = [&](int tt, int& view, int& by, int& bx) {
        view = (tt >= NTILES) ? 1 : 0;
        int t = tt - view * NTILES;
        by = 0;
        while (t >= NT - by) { t -= NT - by; ++by; }
        bx = by + t;
    };
    // issue both tiles' staging DMAs (4096 x 16B, source-side XOR swizzle)
    auto stage = [&](const unsigned char* R, int rT, int cT) {
        #pragma unroll
        for (int stp = 0; stp < 8; ++stp) {
            int s = stp * 256 + tid;
            int row = s >> 4, p = s & 15;
            int cg = p ^ (row & 15);
            const unsigned char* ga = R + (size_t)(rT + row) * DIM + cg * 16;
            const unsigned char* gb = R + (size_t)(cT + row) * DIM + cg * 16;
            __builtin_amdgcn_global_load_lds((glb_uint*)ga, (lds_uint*)&As[s * 16], 16, 0, 0);
            __builtin_amdgcn_global_load_lds((glb_uint*)gb, (lds_uint*)&Bs[s * 16], 16, 0, 0);
        }
    };

    int tt = blockIdx.x;
    if (tt >= TOTAL_TILES) return;
    int view, by, bx;
    decode(tt, view, by, bx);
    stage(view ? R1 : R0, by * BM, bx * BM);

    for (;;) {
        __syncthreads();   // compiler adds vmcnt(0): this tile's DMAs landed

        floatx4 acc[4][4] = {};
        #pragma unroll
        for (int kk = 0; kk < 8; ++kk) {
            long af[4], bf[4];
            int c = kk * 4 + q;
            int ch = c >> 1, hh = (c & 1) * 8;
            #pragma unroll
            for (int tr = 0; tr < 4; ++tr) {
                int ra = wy * 64 + tr * 16 + m;
                af[tr] = *(const long*)&As[ra * DIM + (ch ^ (ra & 15)) * 16 + hh];
                int rb = wx * 64 + tr * 16 + m;
                bf[tr] = *(const long*)&Bs[rb * DIM + (ch ^ (rb & 15)) * 16 + hh];
            }
            #pragma unroll
            for (int i = 0; i < 4; ++i)
                #pragma unroll
                for (int j = 0; j < 4; ++j)
                    acc[i][j] = __builtin_amdgcn_mfma_f32_16x16x32_fp8_fp8(af[i], bf[j], acc[i][j], 0, 0, 0);
        }

        __syncthreads();   // all waves' ds_reads done -> LDS may be overwritten

        // Save current tile coords, then launch next tile's DMAs so they
        // overlap the register-only epilogue below.
        int crT = by * BM, ccT = bx * BM;
        int cdiag = (bx == by);
        float* P = part + (size_t)tt * PSTRIDE;

        tt += GRID_BLOCKS;
        bool more = (tt < TOTAL_TILES);
        if (more) {
            decode(tt, view, by, bx);
            stage(view ? R1 : R0, by * BM, bx * BM);
        }

        // Epilogue. C/D layout: col = m, row = q*4 + r (dtype-independent).
        float rs[4][4] = {};
        float cs[4] = {0.f, 0.f, 0.f, 0.f};
        #pragma unroll
        for (int i = 0; i < 4; ++i)
            #pragma unroll
            for (int j = 0; j < 4; ++j) {
                int gcol = ccT + wx * 64 + j * 16 + m;
                #pragma unroll
                for (int r = 0; r < 4; ++r) {
                    int grow = crT + wy * 64 + i * 16 + q * 4 + r;
                    float e = (grow == gcol) ? 0.0f : __expf(acc[i][j][r] * INV_T);
                    rs[i][r] += e;
                    cs[j] += e;
                }
            }
        #pragma unroll
        for (int off = 1; off < 16; off <<= 1)
            #pragma unroll
            for (int i = 0; i < 4; ++i)
                #pragma unroll
                for (int r = 0; r < 4; ++r)
                    rs[i][r] += __shfl_xor(rs[i][r], off);
        if (m == 0) {
            #pragma unroll
            for (int i = 0; i < 4; ++i) {
                float4 v = make_float4(rs[i][0], rs[i][1], rs[i][2], rs[i][3]);
                *(float4*)&P[wx * 128 + wy * 64 + i * 16 + q * 4] = v;
            }
        }
        #pragma unroll
        for (int off = 16; off < 64; off <<= 1)
            #pragma unroll
            for (int j = 0; j < 4; ++j)
                cs[j] += __shfl_xor(cs[j], off);
        if (q == 0) {
            #pragma unroll
            for (int j = 0; j < 4; ++j)
                P[256 + wy * 128 + wx * 64 + j * 16 + m] = cdiag ? 0.0f : cs[j];
        }

        if (!more) break;
    }
}

// Kernel 3: per-row denom gather (L2-resident) + loss reduce.
__global__ __launch_bounds__(256) void finalize_kernel(
    const float* __restrict__ part, const float* __restrict__ pos,
    float* __restrict__ out)
{
    int g = blockIdx.x * 256 + threadIdx.x;      // 0..8191
    int v = g >> 12, r = g & (N_ROWS - 1);
    int b = r >> 7, l = r & 127;
    const float* P = part + (size_t)v * NTILES * PSTRIDE;

    float d = 0.f;
    int t0 = b * NT - (b * (b - 1)) / 2;         // tile (b, b)
    for (int k = 0; k < NT - b; ++k) {           // row parts: tiles (b, bx>=b)
        const float* T = P + (size_t)(t0 + k) * PSTRIDE;
        d += T[l] + T[128 + l];                  // both wx halves
    }
    for (int by = 0; by <= b; ++by) {            // col parts: tiles (by<=b, b)
        int tb = by * NT - (by * (by - 1)) / 2 + (b - by);
        const float* T = P + (size_t)tb * PSTRIDE;
        d += T[256 + l] + T[384 + l];            // both wy halves
    }
    float p = pos[r];
    float s = __logf(d + __expf(p)) - p;
    #pragma unroll
    for (int off = 1; off < 64; off <<= 1) s += __shfl_xor(s, off);
    if ((threadIdx.x & 63) == 0)
        atomicAdd(out, s * (1.0f / (2 * N_ROWS)));
}

extern "C" void kernel_launch(void* const* d_in, const int* in_sizes, int n_in,
                              void* d_out, int out_size, void* d_ws, size_t ws_size,
                              hipStream_t stream) {
    const float* z_i = (const float*)d_in[0];
    const float* z_j = (const float*)d_in[1];
    char* ws = (char*)d_ws;
    unsigned char* R0 = (unsigned char*)ws;                          // 1 MB fp8
    unsigned char* R1 = (unsigned char*)(ws + (1u << 20));           // 1 MB fp8
    float* pos  = (float*)(ws + (2u << 20));                         // 16 KB
    float* part = (float*)(ws + (2u << 20) + (64u << 10));           // 2.16 MB

    normalize_kernel<<<N_ROWS / 4, 256, 0, stream>>>(z_i, z_j, R0, R1, pos,
                                                     (float*)d_out);
    gemm_sym<<<GRID_BLOCKS, 256, 0, stream>>>(R0, R1, part);
    finalize_kernel<<<2 * N_ROWS / 256, 256, 0, stream>>>(part, pos, (float*)d_out);
}